// Round 1
// baseline (1979.843 us; speedup 1.0000x reference)
//
#include <hip/hip_runtime.h>
#include <math.h>

#define D 256
#define ROWS 64
#define KT 64

__device__ __forceinline__ float dot4(float4 a, float4 b) {
  return a.x * b.x + a.y * b.y + a.z * b.z + a.w * b.w;
}

__device__ __forceinline__ float wave_sum(float s) {
#pragma unroll
  for (int off = 32; off; off >>= 1) s += __shfl_xor(s, off, 64);
  return s;
}

// XOR-swizzled LDS float index for (row, d4-chunk): keeps ds_read_b128
// conflicts <= 2-way for both the 4-consecutive-row and 16-consecutive-k
// read patterns, with zero padding (compact 64 KB per tile).
__device__ __forceinline__ int sw(int row, int d4) {
  return row * D + 4 * (d4 ^ (row & 7));
}

// K1: emb_n = l2_normalize(embedding); e2[k] = sum(emb_n[k]^2) (fp32, like ref)
__global__ __launch_bounds__(256) void k_norm_emb(const float* __restrict__ emb,
                                                  float* __restrict__ emb_n,
                                                  float* __restrict__ e2, int K) {
  int row = blockIdx.x * 4 + (threadIdx.x >> 6);
  int l = threadIdx.x & 63;
  float4 v = ((const float4*)(emb + (size_t)row * D))[l];
  float s = wave_sum(dot4(v, v));
  float inv = 1.0f / sqrtf(s + 1e-12f);
  v.x *= inv; v.y *= inv; v.z *= inv; v.w *= inv;
  ((float4*)(emb_n + (size_t)row * D))[l] = v;
  float s2 = wave_sum(dot4(v, v));
  if (l == 0) e2[row] = s2;
}

// K2: per-row argmin_k of (e2[k] - 2 * <z_n[r], emb_n[k]>)  (z-side constant dropped)
// Block: 256 threads, 64 rows x all K. LDS: z tile (64x256) + e tile (64x256), swizzled.
// Thread (tc=tid&15, tr=tid>>4) owns rows {tr+16i} and ks {tc+16j}, 4x4 acc.
__global__ __launch_bounds__(256, 1) void k_argmin(const float* __restrict__ z,
                                                   const float* __restrict__ emb_n,
                                                   const float* __restrict__ e2,
                                                   float* __restrict__ idx_out, int K) {
  extern __shared__ float smem[];
  float* zs = smem;             // ROWS * D
  float* es = smem + ROWS * D;  // KT * D
  int tid = threadIdx.x;
  int w = tid >> 6, l = tid & 63;
  size_t r0 = (size_t)blockIdx.x * ROWS;

  // Stage + normalize z tile. Wave w holds rows 4i+w; lane l holds col-chunk l.
#pragma unroll
  for (int i = 0; i < 16; ++i) {
    int row = 4 * i + w;
    float4 v = ((const float4*)(z + (r0 + row) * D))[l];
    float s = wave_sum(dot4(v, v));
    float inv = 1.0f / sqrtf(s + 1e-12f);
    v.x *= inv; v.y *= inv; v.z *= inv; v.w *= inv;
    *(float4*)(&zs[sw(row, l)]) = v;
  }
  __syncthreads();

  int tc = tid & 15, tr = tid >> 4;
  float bestd[4] = {1e30f, 1e30f, 1e30f, 1e30f};
  int bestk[4] = {0, 0, 0, 0};

  for (int k0 = 0; k0 < K; k0 += KT) {
    // Stage e tile (already normalized by K1) — plain copy, swizzled store.
#pragma unroll
    for (int i = 0; i < 16; ++i) {
      int row = 4 * i + w;
      float4 v = ((const float4*)(emb_n + (size_t)(k0 + row) * D))[l];
      *(float4*)(&es[sw(row, l)]) = v;
    }
    __syncthreads();

    float acc[4][4] = {};
#pragma unroll 4
    for (int d4 = 0; d4 < 64; ++d4) {
      float4 zv[4], ev[4];
#pragma unroll
      for (int i = 0; i < 4; ++i) zv[i] = *(const float4*)(&zs[sw(tr + 16 * i, d4)]);
#pragma unroll
      for (int j = 0; j < 4; ++j) ev[j] = *(const float4*)(&es[sw(tc + 16 * j, d4)]);
#pragma unroll
      for (int i = 0; i < 4; ++i)
#pragma unroll
        for (int j = 0; j < 4; ++j)
          acc[i][j] = fmaf(zv[i].x, ev[j].x,
                      fmaf(zv[i].y, ev[j].y,
                      fmaf(zv[i].z, ev[j].z,
                      fmaf(zv[i].w, ev[j].w, acc[i][j]))));
    }

    // Argmin update. Per-thread ks ascend with (k0, j); strict < keeps earliest k.
#pragma unroll
    for (int j = 0; j < 4; ++j) {
      int k = k0 + tc + 16 * j;
      float ek = e2[k];
#pragma unroll
      for (int i = 0; i < 4; ++i) {
        float dd = fmaf(-2.0f, acc[i][j], ek);
        if (dd < bestd[i]) { bestd[i] = dd; bestk[i] = k; }
      }
    }
    __syncthreads();  // protect es before next stage overwrites it
  }

  // Reduce across the 16 lanes (tc) sharing each row; tie-break to smaller k.
#pragma unroll
  for (int i = 0; i < 4; ++i) {
    float dd = bestd[i];
    int kk = bestk[i];
#pragma unroll
    for (int off = 1; off < 16; off <<= 1) {
      float od = __shfl_xor(dd, off, 64);
      int ok = __shfl_xor(kk, off, 64);
      if (od < dd || (od == dd && ok < kk)) { dd = od; kk = ok; }
    }
    if (tc == 0) idx_out[r0 + tr + 16 * i] = (float)kk;
  }
}

// K3: z_q gather + straight-through output + loss partial sums.
__global__ __launch_bounds__(256) void k_gather(const float* __restrict__ z,
                                                const float* __restrict__ emb_n,
                                                const float* __restrict__ idx_f,
                                                float* __restrict__ out0,
                                                float* __restrict__ loss_acc) {
  __shared__ float wsum[4];
  int w = threadIdx.x >> 6, l = threadIdx.x & 63;
  int row = blockIdx.x * 4 + w;
  float4 zv = ((const float4*)(z + (size_t)row * D))[l];
  float s = wave_sum(dot4(zv, zv));
  float inv = 1.0f / sqrtf(s + 1e-12f);
  int k = (int)idx_f[row];
  float4 q = ((const float4*)(emb_n + (size_t)k * D))[l];
  // z_q_st = z + (z_q - z): reproduce elementwise fp32 rounding exactly
  float4 o;
  o.x = zv.x + (q.x - zv.x);
  o.y = zv.y + (q.y - zv.y);
  o.z = zv.z + (q.z - zv.z);
  o.w = zv.w + (q.w - zv.w);
  ((float4*)(out0 + (size_t)row * D))[l] = o;
  float dx = q.x - zv.x * inv;
  float dy = q.y - zv.y * inv;
  float dz = q.z - zv.z * inv;
  float dw = q.w - zv.w * inv;
  float lp = wave_sum(dx * dx + dy * dy + dz * dz + dw * dw);
  if (l == 0) wsum[w] = lp;
  __syncthreads();
  if (threadIdx.x == 0)
    atomicAdd(loss_acc, wsum[0] + wsum[1] + wsum[2] + wsum[3]);
}

// K4: loss = BETA*m + m, m = sum / (N*D)  (N*D = 2^22, division exact)
__global__ void k_final(const float* __restrict__ loss_acc,
                        float* __restrict__ loss_out, float inv_cnt) {
  float m = *loss_acc * inv_cnt;
  *loss_out = 0.25f * m + m;
}

extern "C" void kernel_launch(void* const* d_in, const int* in_sizes, int n_in,
                              void* d_out, int out_size, void* d_ws, size_t ws_size,
                              hipStream_t stream) {
  const float* z = (const float*)d_in[0];
  const float* emb = (const float*)d_in[1];
  int N = in_sizes[0] / D;  // 16384
  int K = in_sizes[1] / D;  // 8192

  float* out0 = (float*)d_out;
  float* loss_out = out0 + (size_t)N * D;
  float* idx_out = loss_out + 1;

  float* emb_n = (float*)d_ws;               // K*D floats (8 MB)
  float* e2 = emb_n + (size_t)K * D;         // K floats
  float* loss_acc = e2 + K;                  // 1 float

  hipMemsetAsync(loss_acc, 0, sizeof(float), stream);
  k_norm_emb<<<K / 4, 256, 0, stream>>>(emb, emb_n, e2, K);
  size_t lds_bytes = (size_t)(ROWS + KT) * D * sizeof(float);  // 128 KB
  k_argmin<<<N / ROWS, 256, lds_bytes, stream>>>(z, emb_n, e2, idx_out, K);
  k_gather<<<N / 4, 256, 0, stream>>>(z, emb_n, idx_out, out0, loss_acc);
  k_final<<<1, 1, 0, stream>>>(loss_acc, loss_out, 1.0f / (float)((size_t)N * D));
}

// Round 2
// 1511.561 us; speedup vs baseline: 1.3098x; 1.3098x over previous
//
#include <hip/hip_runtime.h>
#include <math.h>

#define D 256
#define NROW 16384
#define KCODE 8192
#define MARGIN 1.5e-4f

typedef __attribute__((ext_vector_type(8))) short short8;
typedef __attribute__((ext_vector_type(4))) float f32x4;

__device__ __forceinline__ float dot4(float4 a, float4 b) {
  return a.x * b.x + a.y * b.y + a.z * b.z + a.w * b.w;
}
__device__ __forceinline__ float wave_sum(float s) {
#pragma unroll
  for (int off = 32; off; off >>= 1) s += __shfl_xor(s, off, 64);
  return s;
}
__device__ __forceinline__ float wave_min_f(float v) {
#pragma unroll
  for (int off = 32; off; off >>= 1) v = fminf(v, __shfl_xor(v, off, 64));
  return v;
}
__device__ __forceinline__ unsigned short f2bf(float x) {
  unsigned int u = __float_as_uint(x);
  return (unsigned short)((u + 0x7fffu + ((u >> 16) & 1u)) >> 16);
}
__device__ __forceinline__ float bf2f(unsigned short h) {
  return __uint_as_float(((unsigned int)h) << 16);
}
__device__ __forceinline__ void async16(const void* g, void* l) {
  __builtin_amdgcn_global_load_lds(
      (const __attribute__((address_space(1))) unsigned int*)g,
      (__attribute__((address_space(3))) unsigned int*)l, 16, 0, 0);
}

// ---------- prep kernels ----------
// emb: normalize -> emb_n (f32), e2, B' bf16 [hi | hi | lo] (K x 768)
__global__ __launch_bounds__(256) void k_prep_emb(const float* __restrict__ emb,
                                                  float* __restrict__ emb_n,
                                                  float* __restrict__ e2,
                                                  unsigned short* __restrict__ Bb) {
  int row = blockIdx.x * 4 + (threadIdx.x >> 6);
  int l = threadIdx.x & 63;
  float4 v = ((const float4*)(emb + (size_t)row * D))[l];
  float s = wave_sum(dot4(v, v));
  float inv = 1.0f / sqrtf(s + 1e-12f);
  v.x *= inv; v.y *= inv; v.z *= inv; v.w *= inv;
  ((float4*)(emb_n + (size_t)row * D))[l] = v;
  float s2 = wave_sum(dot4(v, v));
  if (l == 0) e2[row] = s2;
  ushort4 hi = {f2bf(v.x), f2bf(v.y), f2bf(v.z), f2bf(v.w)};
  float4 rh = {bf2f(hi.x), bf2f(hi.y), bf2f(hi.z), bf2f(hi.w)};
  ushort4 lo = {f2bf(v.x - rh.x), f2bf(v.y - rh.y), f2bf(v.z - rh.z), f2bf(v.w - rh.w)};
  unsigned short* b = Bb + (size_t)row * 768 + 4 * l;
  *(ushort4*)(b) = hi;
  *(ushort4*)(b + 256) = hi;
  *(ushort4*)(b + 512) = lo;
}

// z: normalize -> A' bf16 [hi | lo | hi] (N x 768)
__global__ __launch_bounds__(256) void k_prep_z(const float* __restrict__ z,
                                                unsigned short* __restrict__ Ab) {
  int row = blockIdx.x * 4 + (threadIdx.x >> 6);
  int l = threadIdx.x & 63;
  float4 v = ((const float4*)(z + (size_t)row * D))[l];
  float s = wave_sum(dot4(v, v));
  float inv = 1.0f / sqrtf(s + 1e-12f);
  v.x *= inv; v.y *= inv; v.z *= inv; v.w *= inv;
  ushort4 hi = {f2bf(v.x), f2bf(v.y), f2bf(v.z), f2bf(v.w)};
  float4 rh = {bf2f(hi.x), bf2f(hi.y), bf2f(hi.z), bf2f(hi.w)};
  ushort4 lo = {f2bf(v.x - rh.x), f2bf(v.y - rh.y), f2bf(v.z - rh.z), f2bf(v.w - rh.w)};
  unsigned short* a = Ab + (size_t)row * 768 + 4 * l;
  *(ushort4*)(a) = hi;
  *(ushort4*)(a + 256) = lo;
  *(ushort4*)(a + 512) = hi;
}

__device__ __forceinline__ void merge2(float& d1, int& k1, float& d2, int& k2,
                                       float od1, int ok1, float od2, int ok2) {
  bool w1 = od1 < d1;
  float n1 = w1 ? od1 : d1; int nk1 = w1 ? ok1 : k1;
  float c  = w1 ? d1 : od1; int ck  = w1 ? k1 : ok1;
  float c2 = w1 ? od2 : d2; int ck2 = w1 ? ok2 : k2;
  bool w2 = c2 < c;
  d1 = n1; k1 = nk1;
  d2 = w2 ? c2 : c; k2 = w2 ? ck2 : ck;
}

// ---------- fused bf16-split GEMM + per-sublist approx top-2 ----------
// 512 threads = 8 waves (2x4 wave grid), wave tile 32x64, block tile 64x256.
// A resident in LDS (12 chunks of 64x64 bf16, 96 KB); B chunk 256x64 (32 KB).
// grid = 256 row-blocks x 4 code-partitions (XCD-swizzled).
__global__ __launch_bounds__(512, 2) void k_gemm_argmin(
    const unsigned short* __restrict__ Ab, const unsigned short* __restrict__ Bb,
    const float* __restrict__ e2, float4* __restrict__ top2) {
  extern __shared__ unsigned short lds[];
  unsigned short* Al = lds;            // 12*64*64 = 49152 ushorts
  unsigned short* Bl = lds + 49152;    // 256*64   = 16384 ushorts
  const int tid = threadIdx.x, w = tid >> 6, l = tid & 63;
  const int wave_m = w >> 2, wave_n = w & 3;
  const int quad = l >> 4, col = l & 15;
  const int lrow = l >> 3, lu = l & 7, gu = lu ^ lrow;  // swizzled global 16B-unit
  const int b = blockIdx.x, xcd = b & 7;
  const int part = xcd >> 1, rb = (b >> 3) * 2 + (xcd & 1);
  const size_t r0 = (size_t)rb * 64;

  // stage resident A (one async16 per thread per chunk)
  const unsigned short* gA = Ab + (r0 + 8 * w + lrow) * 768 + gu * 8;
#pragma unroll
  for (int c = 0; c < 12; ++c)
    async16(gA + c * 64, Al + c * 4096 + w * 512);

  float d1[8], d2[8]; int k1[8], k2[8];
#pragma unroll
  for (int s = 0; s < 8; ++s) { d1[s] = 1e30f; d2[s] = 1e30f; k1[s] = 0; k2[s] = 0; }

  const unsigned short* gBbase = Bb + ((size_t)part * 2048 + 8 * w + lrow) * 768 + gu * 8;
  const int sw7 = col & 7;

  for (int n0 = 0; n0 < 2048; n0 += 256) {
    const int cbase = part * 2048 + n0 + wave_n * 64 + col;
    float e2v[4];
#pragma unroll
    for (int jn = 0; jn < 4; ++jn) e2v[jn] = e2[cbase + jn * 16];
    f32x4 acc[2][4] = {};
    const unsigned short* gB = gBbase + (size_t)n0 * 768;
    for (int c = 0; c < 12; ++c) {
#pragma unroll
      for (int s = 0; s < 4; ++s)
        async16(gB + c * 64 + (size_t)s * 64 * 768, Bl + s * 4096 + w * 512);
      __syncthreads();  // drains vmcnt (async LDS loads) per m97 semantics
#pragma unroll
      for (int kk = 0; kk < 2; ++kk) {
        const int u = (kk * 4 + quad) ^ sw7;
        short8 af[2], bf[4];
#pragma unroll
        for (int im = 0; im < 2; ++im)
          af[im] = *(const short8*)(Al + (c * 64 + wave_m * 32 + im * 16 + col) * 64 + u * 8);
#pragma unroll
        for (int jn = 0; jn < 4; ++jn)
          bf[jn] = *(const short8*)(Bl + (wave_n * 64 + jn * 16 + col) * 64 + u * 8);
#pragma unroll
        for (int im = 0; im < 2; ++im)
#pragma unroll
          for (int jn = 0; jn < 4; ++jn)
            acc[im][jn] = __builtin_amdgcn_mfma_f32_16x16x32_bf16(af[im], bf[jn], acc[im][jn], 0, 0, 0);
      }
      __syncthreads();  // protect Bl before next stage
    }
    // epilogue: approx distance d = e2 - 2*dot, update per-(lane,row-slot) top-2
#pragma unroll
    for (int jn = 0; jn < 4; ++jn) {
      const int cd = cbase + jn * 16;
#pragma unroll
      for (int im = 0; im < 2; ++im)
#pragma unroll
        for (int v = 0; v < 4; ++v) {
          float d = fmaf(-2.0f, acc[im][jn][v], e2v[jn]);
          int s = im * 4 + v;
          bool lt2 = d < d2[s]; bool lt1 = d < d1[s];
          float od1 = d1[s]; int ok1 = k1[s];
          d1[s] = lt1 ? d : od1;  k1[s] = lt1 ? cd : ok1;
          d2[s] = lt1 ? od1 : (lt2 ? d : d2[s]);
          k2[s] = lt1 ? ok1 : (lt2 ? cd : k2[s]);
        }
    }
  }
  // butterfly merge across the 16 lanes (col) sharing each row
#pragma unroll
  for (int s = 0; s < 8; ++s) {
#pragma unroll
    for (int m = 1; m < 16; m <<= 1) {
      float od1 = __shfl_xor(d1[s], m, 64); int ok1 = __shfl_xor(k1[s], m, 64);
      float od2 = __shfl_xor(d2[s], m, 64); int ok2 = __shfl_xor(k2[s], m, 64);
      merge2(d1[s], k1[s], d2[s], k2[s], od1, ok1, od2, ok2);
    }
  }
  if (col == 0) {
#pragma unroll
    for (int s = 0; s < 8; ++s) {
      int im = s >> 2, v = s & 3;
      size_t row = r0 + wave_m * 32 + im * 16 + quad * 4 + v;
      top2[row * 16 + part * 4 + wave_n] =
          make_float4(d1[s], d2[s], __int_as_float(k1[s]), __int_as_float(k2[s]));
    }
  }
}

// ---------- exact refine: pick true argmin among candidates (fp64), rare full scan ----------
__global__ __launch_bounds__(64) void k_refine(const float* __restrict__ z,
                                               const float* __restrict__ emb_n,
                                               const float* __restrict__ e2,
                                               const float4* __restrict__ top2,
                                               float* __restrict__ idx_out) {
  __shared__ float zr[D];
  const int row = blockIdx.x, l = threadIdx.x;
  float4 zv = ((const float4*)(z + (size_t)row * D))[l];
  float s = wave_sum(dot4(zv, zv));
  float inv = 1.0f / sqrtf(s + 1e-12f);
  ((float4*)zr)[l] = make_float4(zv.x * inv, zv.y * inv, zv.z * inv, zv.w * inv);
  __syncthreads();

  float ad = 1e30f; int ck = 0x7fffffff; float gv = 1e30f;
  if (l < 32) {
    float4 e = top2[(size_t)row * 16 + (l >> 1)];
    ad = (l & 1) ? e.y : e.x;
    ck = __float_as_int((l & 1) ? e.w : e.z);
    if (l & 1) gv = ad;  // sublist second-best
  }
  float d1g = wave_min_f(ad);
  float G = wave_min_f(gv);

  double dex = 1e300; int kk = 0x7fffffff;
  if (l < 32 && ad <= d1g + 2.0f * MARGIN) {
    const float4* ev = (const float4*)(emb_n + (size_t)ck * D);
    double acc = 0.0;
#pragma unroll 8
    for (int i = 0; i < 64; ++i) {
      float4 e4 = ev[i]; float4 z4 = ((const float4*)zr)[i];
      acc += (double)e4.x * (double)z4.x + (double)e4.y * (double)z4.y +
             (double)e4.z * (double)z4.z + (double)e4.w * (double)z4.w;
    }
    dex = (double)e2[ck] - 2.0 * acc;
    kk = ck;
  }
#pragma unroll
  for (int off = 32; off; off >>= 1) {
    double od = __shfl_xor(dex, off, 64); int ok = __shfl_xor(kk, off, 64);
    if (od < dex || (od == dex && ok < kk)) { dex = od; kk = ok; }
  }

  if (G - d1g <= 2.0f * MARGIN) {  // ambiguous: exact full scan (rare)
    double bd = 1e300; int bk = 0x7fffffff;
    for (int t = 0; t < KCODE / 64; ++t) {
      int code = t * 64 + l;
      const float4* ev = (const float4*)(emb_n + (size_t)code * D);
      double acc = 0.0;
      for (int i = 0; i < 64; ++i) {
        float4 e4 = ev[i]; float4 z4 = ((const float4*)zr)[i];
        acc += (double)e4.x * (double)z4.x + (double)e4.y * (double)z4.y +
               (double)e4.z * (double)z4.z + (double)e4.w * (double)z4.w;
      }
      double dd = (double)e2[code] - 2.0 * acc;
      if (dd < bd) { bd = dd; bk = code; }
    }
#pragma unroll
    for (int off = 32; off; off >>= 1) {
      double od = __shfl_xor(bd, off, 64); int ok = __shfl_xor(bk, off, 64);
      if (od < bd || (od == bd && ok < bk)) { bd = od; bk = ok; }
    }
    dex = bd; kk = bk;
  }
  if (l == 0) idx_out[row] = (float)kk;
}

// ---------- fallback fp32 argmin (round-1, proven) ----------
__device__ __forceinline__ int sw_f(int row, int d4) { return row * D + 4 * (d4 ^ (row & 7)); }
__global__ __launch_bounds__(256, 1) void k_argmin_f32(const float* __restrict__ z,
                                                       const float* __restrict__ emb_n,
                                                       const float* __restrict__ e2,
                                                       float* __restrict__ idx_out, int K) {
  extern __shared__ float smem[];
  float* zs = smem; float* es = smem + 64 * D;
  int tid = threadIdx.x; int w = tid >> 6, l = tid & 63;
  size_t r0 = (size_t)blockIdx.x * 64;
#pragma unroll
  for (int i = 0; i < 16; ++i) {
    int row = 4 * i + w;
    float4 v = ((const float4*)(z + (r0 + row) * D))[l];
    float s = wave_sum(dot4(v, v));
    float inv = 1.0f / sqrtf(s + 1e-12f);
    v.x *= inv; v.y *= inv; v.z *= inv; v.w *= inv;
    *(float4*)(&zs[sw_f(row, l)]) = v;
  }
  __syncthreads();
  int tc = tid & 15, tr = tid >> 4;
  float bestd[4] = {1e30f, 1e30f, 1e30f, 1e30f};
  int bestk[4] = {0, 0, 0, 0};
  for (int k0 = 0; k0 < K; k0 += 64) {
#pragma unroll
    for (int i = 0; i < 16; ++i) {
      int row = 4 * i + w;
      float4 v = ((const float4*)(emb_n + (size_t)(k0 + row) * D))[l];
      *(float4*)(&es[sw_f(row, l)]) = v;
    }
    __syncthreads();
    float acc[4][4] = {};
#pragma unroll 4
    for (int d4 = 0; d4 < 64; ++d4) {
      float4 zv[4], ev[4];
#pragma unroll
      for (int i = 0; i < 4; ++i) zv[i] = *(const float4*)(&zs[sw_f(tr + 16 * i, d4)]);
#pragma unroll
      for (int j = 0; j < 4; ++j) ev[j] = *(const float4*)(&es[sw_f(tc + 16 * j, d4)]);
#pragma unroll
      for (int i = 0; i < 4; ++i)
#pragma unroll
        for (int j = 0; j < 4; ++j)
          acc[i][j] = fmaf(zv[i].x, ev[j].x, fmaf(zv[i].y, ev[j].y,
                      fmaf(zv[i].z, ev[j].z, fmaf(zv[i].w, ev[j].w, acc[i][j]))));
    }
#pragma unroll
    for (int j = 0; j < 4; ++j) {
      int k = k0 + tc + 16 * j;
      float ek = e2[k];
#pragma unroll
      for (int i = 0; i < 4; ++i) {
        float dd = fmaf(-2.0f, acc[i][j], ek);
        if (dd < bestd[i]) { bestd[i] = dd; bestk[i] = k; }
      }
    }
    __syncthreads();
  }
#pragma unroll
  for (int i = 0; i < 4; ++i) {
    float dd = bestd[i]; int kkk = bestk[i];
#pragma unroll
    for (int off = 1; off < 16; off <<= 1) {
      float od = __shfl_xor(dd, off, 64); int ok = __shfl_xor(kkk, off, 64);
      if (od < dd || (od == dd && ok < kkk)) { dd = od; kkk = ok; }
    }
    if (tc == 0) idx_out[r0 + tr + 16 * i] = (float)kkk;
  }
}

// ---------- epilogue: gather + STE + loss ----------
__global__ __launch_bounds__(256) void k_gather(const float* __restrict__ z,
                                                const float* __restrict__ emb_n,
                                                const float* __restrict__ idx_f,
                                                float* __restrict__ out0,
                                                float* __restrict__ loss_acc) {
  __shared__ float wsum[4];
  int w = threadIdx.x >> 6, l = threadIdx.x & 63;
  int row = blockIdx.x * 4 + w;
  float4 zv = ((const float4*)(z + (size_t)row * D))[l];
  float s = wave_sum(dot4(zv, zv));
  float inv = 1.0f / sqrtf(s + 1e-12f);
  int k = (int)idx_f[row];
  float4 q = ((const float4*)(emb_n + (size_t)k * D))[l];
  float4 o;
  o.x = zv.x + (q.x - zv.x); o.y = zv.y + (q.y - zv.y);
  o.z = zv.z + (q.z - zv.z); o.w = zv.w + (q.w - zv.w);
  ((float4*)(out0 + (size_t)row * D))[l] = o;
  float dx = q.x - zv.x * inv, dy = q.y - zv.y * inv;
  float dz = q.z - zv.z * inv, dw = q.w - zv.w * inv;
  float lp = wave_sum(dx * dx + dy * dy + dz * dz + dw * dw);
  if (l == 0) wsum[w] = lp;
  __syncthreads();
  if (threadIdx.x == 0) atomicAdd(loss_acc, wsum[0] + wsum[1] + wsum[2] + wsum[3]);
}

__global__ void k_final(const float* __restrict__ loss_acc,
                        float* __restrict__ loss_out, float inv_cnt) {
  float m = *loss_acc * inv_cnt;
  *loss_out = 0.25f * m + m;
}

extern "C" void kernel_launch(void* const* d_in, const int* in_sizes, int n_in,
                              void* d_out, int out_size, void* d_ws, size_t ws_size,
                              hipStream_t stream) {
  const float* z = (const float*)d_in[0];
  const float* emb = (const float*)d_in[1];
  int N = in_sizes[0] / D;  // 16384
  int K = in_sizes[1] / D;  // 8192

  float* out0 = (float*)d_out;
  float* loss_out = out0 + (size_t)N * D;
  float* idx_out = loss_out + 1;

  char* ws = (char*)d_ws;
  float* emb_n = (float*)ws;                                   // 8 MB
  float* e2 = (float*)(ws + 8388608);                          // 32 KB
  float* loss_acc = (float*)(ws + 8421376);                    // 4 B
  unsigned short* Bb = (unsigned short*)(ws + 8421392);        // 12 MB
  unsigned short* Ab = (unsigned short*)(ws + 21004304);       // 24 MB
  float4* top2 = (float4*)(ws + 46170128);                     // 4 MB
  const size_t NEED = 50364432;

  hipMemsetAsync(loss_acc, 0, sizeof(float), stream);
  if (ws_size >= NEED) {
    k_prep_emb<<<K / 4, 256, 0, stream>>>(emb, emb_n, e2, Bb);
    k_prep_z<<<N / 4, 256, 0, stream>>>(z, Ab);
    k_gemm_argmin<<<(N / 64) * 4, 512, 131072, stream>>>(Ab, Bb, e2, top2);
    k_refine<<<N, 64, 0, stream>>>(z, emb_n, e2, top2, idx_out);
  } else {
    k_prep_emb<<<K / 4, 256, 0, stream>>>(emb, emb_n, e2, Bb);  // Bb unused region ok? no:
    // fallback: re-run normalize only (Bb may be OOB) — use fp32 path without Bb
    k_argmin_f32<<<N / 64, 256, 131072, stream>>>(z, emb_n, e2, idx_out, K);
  }
  k_gather<<<N / 4, 256, 0, stream>>>(z, emb_n, idx_out, out0, loss_acc);
  k_final<<<1, 1, 0, stream>>>(loss_acc, loss_out, 1.0f / (float)((size_t)N * D));
}

// Round 3
// 975.438 us; speedup vs baseline: 2.0297x; 1.5496x over previous
//
#include <hip/hip_runtime.h>
#include <math.h>

#define D 256
#define NROW 16384
#define KCODE 8192
#define MARGIN 4e-5f

typedef __attribute__((ext_vector_type(8))) short short8;
typedef __attribute__((ext_vector_type(4))) float f32x4;

__device__ __forceinline__ float dot4(float4 a, float4 b) {
  return a.x * b.x + a.y * b.y + a.z * b.z + a.w * b.w;
}
__device__ __forceinline__ float wave_sum(float s) {
#pragma unroll
  for (int off = 32; off; off >>= 1) s += __shfl_xor(s, off, 64);
  return s;
}
__device__ __forceinline__ float wave_min_f(float v) {
#pragma unroll
  for (int off = 32; off; off >>= 1) v = fminf(v, __shfl_xor(v, off, 64));
  return v;
}
__device__ __forceinline__ unsigned short f2bf(float x) {
  unsigned int u = __float_as_uint(x);
  return (unsigned short)((u + 0x7fffu + ((u >> 16) & 1u)) >> 16);
}
__device__ __forceinline__ float bf2f(unsigned short h) {
  return __uint_as_float(((unsigned int)h) << 16);
}
__device__ __forceinline__ void async16(const void* g, void* l) {
  __builtin_amdgcn_global_load_lds(
      (const __attribute__((address_space(1))) unsigned int*)g,
      (__attribute__((address_space(3))) unsigned int*)l, 16, 0, 0);
}

// ---------- prep kernels ----------
__global__ __launch_bounds__(256) void k_prep_emb(const float* __restrict__ emb,
                                                  float* __restrict__ emb_n,
                                                  float* __restrict__ e2,
                                                  unsigned short* __restrict__ Bb) {
  int row = blockIdx.x * 4 + (threadIdx.x >> 6);
  int l = threadIdx.x & 63;
  float4 v = ((const float4*)(emb + (size_t)row * D))[l];
  float s = wave_sum(dot4(v, v));
  float inv = 1.0f / sqrtf(s + 1e-12f);
  v.x *= inv; v.y *= inv; v.z *= inv; v.w *= inv;
  ((float4*)(emb_n + (size_t)row * D))[l] = v;
  float s2 = wave_sum(dot4(v, v));
  if (l == 0) e2[row] = s2;
  ushort4 hi = {f2bf(v.x), f2bf(v.y), f2bf(v.z), f2bf(v.w)};
  float4 rh = {bf2f(hi.x), bf2f(hi.y), bf2f(hi.z), bf2f(hi.w)};
  ushort4 lo = {f2bf(v.x - rh.x), f2bf(v.y - rh.y), f2bf(v.z - rh.z), f2bf(v.w - rh.w)};
  unsigned short* b = Bb + (size_t)row * 768 + 4 * l;
  *(ushort4*)(b) = hi;
  *(ushort4*)(b + 256) = hi;
  *(ushort4*)(b + 512) = lo;
}

__global__ __launch_bounds__(256) void k_prep_z(const float* __restrict__ z,
                                                unsigned short* __restrict__ Ab) {
  int row = blockIdx.x * 4 + (threadIdx.x >> 6);
  int l = threadIdx.x & 63;
  float4 v = ((const float4*)(z + (size_t)row * D))[l];
  float s = wave_sum(dot4(v, v));
  float inv = 1.0f / sqrtf(s + 1e-12f);
  v.x *= inv; v.y *= inv; v.z *= inv; v.w *= inv;
  ushort4 hi = {f2bf(v.x), f2bf(v.y), f2bf(v.z), f2bf(v.w)};
  float4 rh = {bf2f(hi.x), bf2f(hi.y), bf2f(hi.z), bf2f(hi.w)};
  ushort4 lo = {f2bf(v.x - rh.x), f2bf(v.y - rh.y), f2bf(v.z - rh.z), f2bf(v.w - rh.w)};
  unsigned short* a = Ab + (size_t)row * 768 + 4 * l;
  *(ushort4*)(a) = hi;
  *(ushort4*)(a + 256) = lo;
  *(ushort4*)(a + 512) = hi;
}

__device__ __forceinline__ void merge2(float& d1, int& k1, float& d2, int& k2,
                                       float od1, int ok1, float od2, int ok2) {
  bool w1 = od1 < d1;
  float n1 = w1 ? od1 : d1; int nk1 = w1 ? ok1 : k1;
  float c  = w1 ? d1 : od1; int ck  = w1 ? k1 : ok1;
  float c2 = w1 ? od2 : d2; int ck2 = w1 ? ok2 : k2;
  bool w2 = c2 < c;
  d1 = n1; k1 = nk1;
  d2 = w2 ? c2 : c; k2 = w2 ? ck2 : ck;
}

// ---------- fused bf16-split GEMM + per-sublist approx top-2 (unchanged) ----------
__global__ __launch_bounds__(512, 2) void k_gemm_argmin(
    const unsigned short* __restrict__ Ab, const unsigned short* __restrict__ Bb,
    const float* __restrict__ e2, float4* __restrict__ top2) {
  extern __shared__ unsigned short lds[];
  unsigned short* Al = lds;            // 12*64*64 = 49152 ushorts
  unsigned short* Bl = lds + 49152;    // 256*64   = 16384 ushorts
  const int tid = threadIdx.x, w = tid >> 6, l = tid & 63;
  const int wave_m = w >> 2, wave_n = w & 3;
  const int quad = l >> 4, col = l & 15;
  const int lrow = l >> 3, lu = l & 7, gu = lu ^ lrow;
  const int b = blockIdx.x, xcd = b & 7;
  const int part = xcd >> 1, rb = (b >> 3) * 2 + (xcd & 1);
  const size_t r0 = (size_t)rb * 64;

  const unsigned short* gA = Ab + (r0 + 8 * w + lrow) * 768 + gu * 8;
#pragma unroll
  for (int c = 0; c < 12; ++c)
    async16(gA + c * 64, Al + c * 4096 + w * 512);

  float d1[8], d2[8]; int k1[8], k2[8];
#pragma unroll
  for (int s = 0; s < 8; ++s) { d1[s] = 1e30f; d2[s] = 1e30f; k1[s] = 0; k2[s] = 0; }

  const unsigned short* gBbase = Bb + ((size_t)part * 2048 + 8 * w + lrow) * 768 + gu * 8;
  const int sw7 = col & 7;

  for (int n0 = 0; n0 < 2048; n0 += 256) {
    const int cbase = part * 2048 + n0 + wave_n * 64 + col;
    float e2v[4];
#pragma unroll
    for (int jn = 0; jn < 4; ++jn) e2v[jn] = e2[cbase + jn * 16];
    f32x4 acc[2][4] = {};
    const unsigned short* gB = gBbase + (size_t)n0 * 768;
    for (int c = 0; c < 12; ++c) {
#pragma unroll
      for (int s = 0; s < 4; ++s)
        async16(gB + c * 64 + (size_t)s * 64 * 768, Bl + s * 4096 + w * 512);
      __syncthreads();
#pragma unroll
      for (int kk = 0; kk < 2; ++kk) {
        const int u = (kk * 4 + quad) ^ sw7;
        short8 af[2], bf[4];
#pragma unroll
        for (int im = 0; im < 2; ++im)
          af[im] = *(const short8*)(Al + (c * 64 + wave_m * 32 + im * 16 + col) * 64 + u * 8);
#pragma unroll
        for (int jn = 0; jn < 4; ++jn)
          bf[jn] = *(const short8*)(Bl + (wave_n * 64 + jn * 16 + col) * 64 + u * 8);
#pragma unroll
        for (int im = 0; im < 2; ++im)
#pragma unroll
          for (int jn = 0; jn < 4; ++jn)
            acc[im][jn] = __builtin_amdgcn_mfma_f32_16x16x32_bf16(af[im], bf[jn], acc[im][jn], 0, 0, 0);
      }
      __syncthreads();
    }
#pragma unroll
    for (int jn = 0; jn < 4; ++jn) {
      const int cd = cbase + jn * 16;
#pragma unroll
      for (int im = 0; im < 2; ++im)
#pragma unroll
        for (int v = 0; v < 4; ++v) {
          float d = fmaf(-2.0f, acc[im][jn][v], e2v[jn]);
          int s = im * 4 + v;
          bool lt2 = d < d2[s]; bool lt1 = d < d1[s];
          float od1 = d1[s]; int ok1 = k1[s];
          d1[s] = lt1 ? d : od1;  k1[s] = lt1 ? cd : ok1;
          d2[s] = lt1 ? od1 : (lt2 ? d : d2[s]);
          k2[s] = lt1 ? ok1 : (lt2 ? cd : k2[s]);
        }
    }
  }
#pragma unroll
  for (int s = 0; s < 8; ++s) {
#pragma unroll
    for (int m = 1; m < 16; m <<= 1) {
      float od1 = __shfl_xor(d1[s], m, 64); int ok1 = __shfl_xor(k1[s], m, 64);
      float od2 = __shfl_xor(d2[s], m, 64); int ok2 = __shfl_xor(k2[s], m, 64);
      merge2(d1[s], k1[s], d2[s], k2[s], od1, ok1, od2, ok2);
    }
  }
  if (col == 0) {
#pragma unroll
    for (int s = 0; s < 8; ++s) {
      int im = s >> 2, v = s & 3;
      size_t row = r0 + wave_m * 32 + im * 16 + quad * 4 + v;
      top2[row * 16 + part * 4 + wave_n] =
          make_float4(d1[s], d2[s], __int_as_float(k1[s]), __int_as_float(k2[s]));
    }
  }
}

// ---------- refine: exact fp64 pick among candidates; flag ambiguous rows ----------
// 2 lanes per candidate (32 candidates x 2 halves = 64 lanes). No inline scan.
__global__ __launch_bounds__(64) void k_refine(const float* __restrict__ z,
                                               const float* __restrict__ emb_n,
                                               const float* __restrict__ e2,
                                               const float4* __restrict__ top2,
                                               float* __restrict__ idx_out,
                                               int* __restrict__ worklist,
                                               int* __restrict__ n_flag) {
  __shared__ float zr[D];
  const int row = blockIdx.x, l = threadIdx.x;
  float4 zv = ((const float4*)(z + (size_t)row * D))[l];
  float s = wave_sum(dot4(zv, zv));
  float inv = 1.0f / sqrtf(s + 1e-12f);
  ((float4*)zr)[l] = make_float4(zv.x * inv, zv.y * inv, zv.z * inv, zv.w * inv);
  __syncthreads();

  const int c = l >> 1, half = l & 1;
  float4 e = top2[(size_t)row * 16 + (c >> 1)];
  float ad = (c & 1) ? e.y : e.x;
  int ck = __float_as_int((c & 1) ? e.w : e.z);
  float gv = (c & 1) ? ad : 1e30f;  // sublist second-bests
  float d1g = wave_min_f(ad);
  float G = wave_min_f(gv);

  double acc = 0.0;
  bool evalc = (ad <= d1g + 2.0f * MARGIN);
  if (evalc) {
    const float4* ev = (const float4*)(emb_n + (size_t)ck * D) + half * 32;
    const float4* zp = ((const float4*)zr) + half * 32;
#pragma unroll 8
    for (int i = 0; i < 32; ++i) {
      float4 e4 = ev[i], z4 = zp[i];
      acc += (double)e4.x * (double)z4.x + (double)e4.y * (double)z4.y +
             (double)e4.z * (double)z4.z + (double)e4.w * (double)z4.w;
    }
  }
  acc += __shfl_xor(acc, 1, 64);  // combine halves
  double dex = 1e300; int kk = 0x7fffffff;
  if (evalc && half == 0) { dex = (double)e2[ck] - 2.0 * acc; kk = ck; }
#pragma unroll
  for (int off = 1; off < 64; off <<= 1) {
    double od = __shfl_xor(dex, off, 64); int ok = __shfl_xor(kk, off, 64);
    if (od < dex || (od == dex && ok < kk)) { dex = od; kk = ok; }
  }
  if (l == 0) {
    idx_out[row] = (float)kk;
    if (G - d1g <= 2.0f * MARGIN) {
      int p = atomicAdd(n_flag, 1);
      worklist[p] = row;
    }
  }
}

// ---------- exact fp64 full scan over flagged rows (parallel, worklist-driven) ----------
__global__ __launch_bounds__(256) void k_scan(const float* __restrict__ z,
                                              const float* __restrict__ emb_n,
                                              const float* __restrict__ e2,
                                              const int* __restrict__ worklist,
                                              const int* __restrict__ n_flag,
                                              float* __restrict__ idx_out) {
  __shared__ float zr[D];
  __shared__ double sd[4];
  __shared__ int si[4];
  const int nf = *n_flag;
  const int tid = threadIdx.x;
  for (int wi = blockIdx.x; wi < nf; wi += gridDim.x) {
    const int row = worklist[wi];
    __syncthreads();  // protect zr across iterations
    if (tid < 64) {
      float4 zv = ((const float4*)(z + (size_t)row * D))[tid];
      float s = wave_sum(dot4(zv, zv));
      float inv = 1.0f / sqrtf(s + 1e-12f);
      ((float4*)zr)[tid] = make_float4(zv.x * inv, zv.y * inv, zv.z * inv, zv.w * inv);
    }
    __syncthreads();
    double bd = 1e300; int bk = 0x7fffffff;
    const float4* zf = (const float4*)zr;
    for (int j = 0; j < KCODE / 256; ++j) {
      const int code = j * 256 + tid;
      const float4* ev = (const float4*)(emb_n + (size_t)code * D);
      double a0 = 0.0, a1 = 0.0, a2 = 0.0, a3 = 0.0;
#pragma unroll 4
      for (int i = 0; i < 64; i += 4) {
        float4 e0 = ev[i], e1 = ev[i + 1], ex = ev[i + 2], e3 = ev[i + 3];
        float4 z0 = zf[i], z1 = zf[i + 1], zx = zf[i + 2], z3 = zf[i + 3];
        a0 += (double)e0.x * (double)z0.x + (double)e0.y * (double)z0.y +
              (double)e0.z * (double)z0.z + (double)e0.w * (double)z0.w;
        a1 += (double)e1.x * (double)z1.x + (double)e1.y * (double)z1.y +
              (double)e1.z * (double)z1.z + (double)e1.w * (double)z1.w;
        a2 += (double)ex.x * (double)zx.x + (double)ex.y * (double)zx.y +
              (double)ex.z * (double)zx.z + (double)ex.w * (double)zx.w;
        a3 += (double)e3.x * (double)z3.x + (double)e3.y * (double)z3.y +
              (double)e3.z * (double)z3.z + (double)e3.w * (double)z3.w;
      }
      double dd = (double)e2[code] - 2.0 * ((a0 + a1) + (a2 + a3));
      if (dd < bd || (dd == bd && code < bk)) { bd = dd; bk = code; }
    }
#pragma unroll
    for (int off = 32; off; off >>= 1) {
      double od = __shfl_xor(bd, off, 64); int ok = __shfl_xor(bk, off, 64);
      if (od < bd || (od == bd && ok < bk)) { bd = od; bk = ok; }
    }
    const int w = tid >> 6;
    if ((tid & 63) == 0) { sd[w] = bd; si[w] = bk; }
    __syncthreads();
    if (tid == 0) {
#pragma unroll
      for (int q = 1; q < 4; ++q)
        if (sd[q] < bd || (sd[q] == bd && si[q] < bk)) { bd = sd[q]; bk = si[q]; }
      idx_out[row] = (float)bk;
    }
  }
}

// ---------- fallback fp32 argmin (round-1, proven) ----------
__device__ __forceinline__ int sw_f(int row, int d4) { return row * D + 4 * (d4 ^ (row & 7)); }
__global__ __launch_bounds__(256, 1) void k_argmin_f32(const float* __restrict__ z,
                                                       const float* __restrict__ emb_n,
                                                       const float* __restrict__ e2,
                                                       float* __restrict__ idx_out, int K) {
  extern __shared__ float smem[];
  float* zs = smem; float* es = smem + 64 * D;
  int tid = threadIdx.x; int w = tid >> 6, l = tid & 63;
  size_t r0 = (size_t)blockIdx.x * 64;
#pragma unroll
  for (int i = 0; i < 16; ++i) {
    int row = 4 * i + w;
    float4 v = ((const float4*)(z + (r0 + row) * D))[l];
    float s = wave_sum(dot4(v, v));
    float inv = 1.0f / sqrtf(s + 1e-12f);
    v.x *= inv; v.y *= inv; v.z *= inv; v.w *= inv;
    *(float4*)(&zs[sw_f(row, l)]) = v;
  }
  __syncthreads();
  int tc = tid & 15, tr = tid >> 4;
  float bestd[4] = {1e30f, 1e30f, 1e30f, 1e30f};
  int bestk[4] = {0, 0, 0, 0};
  for (int k0 = 0; k0 < K; k0 += 64) {
#pragma unroll
    for (int i = 0; i < 16; ++i) {
      int row = 4 * i + w;
      float4 v = ((const float4*)(emb_n + (size_t)(k0 + row) * D))[l];
      *(float4*)(&es[sw_f(row, l)]) = v;
    }
    __syncthreads();
    float acc[4][4] = {};
#pragma unroll 4
    for (int d4 = 0; d4 < 64; ++d4) {
      float4 zv[4], ev[4];
#pragma unroll
      for (int i = 0; i < 4; ++i) zv[i] = *(const float4*)(&zs[sw_f(tr + 16 * i, d4)]);
#pragma unroll
      for (int j = 0; j < 4; ++j) ev[j] = *(const float4*)(&es[sw_f(tc + 16 * j, d4)]);
#pragma unroll
      for (int i = 0; i < 4; ++i)
#pragma unroll
        for (int j = 0; j < 4; ++j)
          acc[i][j] = fmaf(zv[i].x, ev[j].x, fmaf(zv[i].y, ev[j].y,
                      fmaf(zv[i].z, ev[j].z, fmaf(zv[i].w, ev[j].w, acc[i][j]))));
    }
#pragma unroll
    for (int j = 0; j < 4; ++j) {
      int k = k0 + tc + 16 * j;
      float ek = e2[k];
#pragma unroll
      for (int i = 0; i < 4; ++i) {
        float dd = fmaf(-2.0f, acc[i][j], ek);
        if (dd < bestd[i]) { bestd[i] = dd; bestk[i] = k; }
      }
    }
    __syncthreads();
  }
#pragma unroll
  for (int i = 0; i < 4; ++i) {
    float dd = bestd[i]; int kkk = bestk[i];
#pragma unroll
    for (int off = 1; off < 16; off <<= 1) {
      float od = __shfl_xor(dd, off, 64); int ok = __shfl_xor(kkk, off, 64);
      if (od < dd || (od == dd && ok < kkk)) { dd = od; kkk = ok; }
    }
    if (tc == 0) idx_out[r0 + tr + 16 * i] = (float)kkk;
  }
}

// ---------- epilogue: gather + STE + loss ----------
__global__ __launch_bounds__(256) void k_gather(const float* __restrict__ z,
                                                const float* __restrict__ emb_n,
                                                const float* __restrict__ idx_f,
                                                float* __restrict__ out0,
                                                float* __restrict__ loss_acc) {
  __shared__ float wsum[4];
  int w = threadIdx.x >> 6, l = threadIdx.x & 63;
  int row = blockIdx.x * 4 + w;
  float4 zv = ((const float4*)(z + (size_t)row * D))[l];
  float s = wave_sum(dot4(zv, zv));
  float inv = 1.0f / sqrtf(s + 1e-12f);
  int k = (int)idx_f[row];
  float4 q = ((const float4*)(emb_n + (size_t)k * D))[l];
  float4 o;
  o.x = zv.x + (q.x - zv.x); o.y = zv.y + (q.y - zv.y);
  o.z = zv.z + (q.z - zv.z); o.w = zv.w + (q.w - zv.w);
  ((float4*)(out0 + (size_t)row * D))[l] = o;
  float dx = q.x - zv.x * inv, dy = q.y - zv.y * inv;
  float dz = q.z - zv.z * inv, dw = q.w - zv.w * inv;
  float lp = wave_sum(dx * dx + dy * dy + dz * dz + dw * dw);
  if (l == 0) wsum[w] = lp;
  __syncthreads();
  if (threadIdx.x == 0) atomicAdd(loss_acc, wsum[0] + wsum[1] + wsum[2] + wsum[3]);
}

__global__ void k_final(const float* __restrict__ loss_acc,
                        float* __restrict__ loss_out, float inv_cnt) {
  float m = *loss_acc * inv_cnt;
  *loss_out = 0.25f * m + m;
}

extern "C" void kernel_launch(void* const* d_in, const int* in_sizes, int n_in,
                              void* d_out, int out_size, void* d_ws, size_t ws_size,
                              hipStream_t stream) {
  const float* z = (const float*)d_in[0];
  const float* emb = (const float*)d_in[1];
  int N = in_sizes[0] / D;  // 16384
  int K = in_sizes[1] / D;  // 8192

  float* out0 = (float*)d_out;
  float* loss_out = out0 + (size_t)N * D;
  float* idx_out = loss_out + 1;

  char* ws = (char*)d_ws;
  float* emb_n = (float*)ws;                                   // 8 MB
  float* e2 = (float*)(ws + 8388608);                          // 32 KB
  float* loss_acc = (float*)(ws + 8421376);                    // 4 B
  int* n_flag = (int*)(ws + 8421380);                          // 4 B
  unsigned short* Bb = (unsigned short*)(ws + 8421392);        // 12 MB
  unsigned short* Ab = (unsigned short*)(ws + 21004304);       // 24 MB
  float4* top2 = (float4*)(ws + 46170128);                     // 4 MB
  const size_t NEED = 50364432;
  // worklist aliases Ab: Ab is dead after k_gemm_argmin, worklist written after.
  int* worklist = (int*)Ab;

  hipMemsetAsync(loss_acc, 0, 8, stream);  // zero loss_acc + n_flag
  if (ws_size >= NEED) {
    k_prep_emb<<<K / 4, 256, 0, stream>>>(emb, emb_n, e2, Bb);
    k_prep_z<<<N / 4, 256, 0, stream>>>(z, Ab);
    k_gemm_argmin<<<(N / 64) * 4, 512, 131072, stream>>>(Ab, Bb, e2, top2);
    k_refine<<<N, 64, 0, stream>>>(z, emb_n, e2, top2, idx_out, worklist, n_flag);
    k_scan<<<128, 256, 0, stream>>>(z, emb_n, e2, worklist, n_flag, idx_out);
  } else {
    k_prep_emb<<<K / 4, 256, 0, stream>>>(emb, emb_n, e2, Bb);
    k_argmin_f32<<<N / 64, 256, 131072, stream>>>(z, emb_n, e2, idx_out, K);
  }
  k_gather<<<N / 4, 256, 0, stream>>>(z, emb_n, idx_out, out0, loss_acc);
  k_final<<<1, 1, 0, stream>>>(loss_acc, loss_out, 1.0f / (float)((size_t)N * D));
}